// Round 1
// baseline (207.580 us; speedup 1.0000x reference)
//
#include <hip/hip_runtime.h>
#include <hip/hip_bf16.h>
#include <stdint.h>

typedef __attribute__((ext_vector_type(8))) __bf16 bf16x8;
typedef __attribute__((ext_vector_type(4))) float f32x4;

#define MFMA16(a, b, c) __builtin_amdgcn_mfma_f32_16x16x32_bf16(a, b, c, 0, 0, 0)

typedef const __attribute__((address_space(1))) uint32_t* gas_ptr;
typedef __attribute__((address_space(3))) uint32_t* lds_ptr;

static __device__ __forceinline__ ushort f2b(float f) {
  union { float f; uint32_t u; } x; x.f = f;
  uint32_t u = x.u + 0x7fffu + ((x.u >> 16) & 1u);
  return (ushort)(u >> 16);
}

static __device__ __forceinline__ void g2lds16(const void* g, void* l) {
  __builtin_amdgcn_global_load_lds((gas_ptr)(uintptr_t)g, (lds_ptr)(uintptr_t)l, 16, 0, 0);
}

// ---------------- x fp32 -> bf16 ----------------
__global__ void cvt_x(const float* __restrict__ in, ushort* __restrict__ out, int n) {
  int i = (blockIdx.x * blockDim.x + threadIdx.x) * 4;
  if (i < n) {
    float4 v = *(const float4*)(in + i);
    ushort4 o;
    o.x = f2b(v.x); o.y = f2b(v.y); o.z = f2b(v.z); o.w = f2b(v.w);
    *(ushort4*)(out + i) = o;
  }
}

// ---------------- W fp32 [K][N] -> bf16 [N][K] (B^T layout) ----------------
__global__ __launch_bounds__(256) void transpose_w(const float* __restrict__ in,
                                                   ushort* __restrict__ out, int K, int N) {
  __shared__ ushort tile[64][65];
  int n0 = blockIdx.x * 64, k0 = blockIdx.y * 64;
  int t = threadIdx.x;
#pragma unroll
  for (int i = 0; i < 16; ++i) {
    int idx = i * 256 + t;
    int r = idx >> 6, c = idx & 63;
    tile[r][c] = f2b(in[(size_t)(k0 + r) * N + n0 + c]);
  }
  __syncthreads();
#pragma unroll
  for (int i = 0; i < 16; ++i) {
    int idx = i * 256 + t;
    int r = idx >> 6, c = idx & 63;  // r = n index, c = k index
    out[(size_t)(n0 + r) * K + k0 + c] = tile[c][r];
  }
}

// ---------------- bf16 GEMM: C[M][N] = A[M][K] * Bt[N][K]^T (+bias) ----------------
// 128x128 tile, BK=64, 4 waves (2x2), global_load_lds staging, XOR-swizzled LDS.
template <bool BIAS>
__global__ __launch_bounds__(256) void gemm_bt(const ushort* __restrict__ A,
                                               const ushort* __restrict__ Bt,
                                               float* __restrict__ C,
                                               const float* __restrict__ bias,
                                               int M, int N, int K) {
  __shared__ ushort lA[128 * 64];
  __shared__ ushort lB[128 * 64];
  const int t = threadIdx.x;
  const int lane = t & 63;
  const int bm = blockIdx.y * 128, bn = blockIdx.x * 128;
  const int wid = t >> 6, wr = wid >> 1, wc = wid & 1;

  f32x4 acc[4][4] = {};

  for (int k0 = 0; k0 < K; k0 += 64) {
#pragma unroll
    for (int i = 0; i < 4; ++i) {
      int ci = i * 256 + t;
      int r = ci >> 3, cs = ci & 7;
      int cg = (cs ^ (r & 7)) * 8;  // pre-swizzled global source column (bf16 units)
      g2lds16(A + (size_t)(bm + r) * K + k0 + cg, (ushort*)lA + ci * 8);
      g2lds16(Bt + (size_t)(bn + r) * K + k0 + cg, (ushort*)lB + ci * 8);
    }
    __syncthreads();
#pragma unroll
    for (int kk = 0; kk < 2; ++kk) {
      bf16x8 af[4], bfr[4];
#pragma unroll
      for (int m = 0; m < 4; ++m) {
        int row = wr * 64 + m * 16 + (lane & 15);
        int cb = kk * 64 + ((lane >> 4) << 4);
        int sw = cb ^ ((row & 7) << 4);
        af[m] = *(const bf16x8*)((const char*)lA + row * 128 + sw);
      }
#pragma unroll
      for (int n = 0; n < 4; ++n) {
        int row = wc * 64 + n * 16 + (lane & 15);
        int cb = kk * 64 + ((lane >> 4) << 4);
        int sw = cb ^ ((row & 7) << 4);
        bfr[n] = *(const bf16x8*)((const char*)lB + row * 128 + sw);
      }
#pragma unroll
      for (int m = 0; m < 4; ++m)
#pragma unroll
        for (int n = 0; n < 4; ++n) acc[m][n] = MFMA16(af[m], bfr[n], acc[m][n]);
    }
    __syncthreads();
  }
#pragma unroll
  for (int m = 0; m < 4; ++m) {
#pragma unroll
    for (int n = 0; n < 4; ++n) {
      int col = bn + wc * 64 + n * 16 + (lane & 15);
      float b = BIAS ? bias[col] : 0.f;
#pragma unroll
      for (int r = 0; r < 4; ++r) {
        int row = bm + wr * 64 + m * 16 + ((lane >> 4) << 2) + r;
        C[(size_t)row * N + col] = acc[m][n][r] + b;
      }
    }
  }
}

// ---------------- split qkv fp32 -> Qs (x0.125), K' (+rel), V^T, all bf16 ----------------
__global__ __launch_bounds__(256) void pack_qkv(const float* __restrict__ qkv,
                                                const float* __restrict__ bqkv,
                                                const float* __restrict__ rel,
                                                ushort* __restrict__ Qs,
                                                ushort* __restrict__ Kp,
                                                ushort* __restrict__ Vt, int L) {
  __shared__ ushort vt[64][65];
  const int h = blockIdx.y;
  const int l0 = blockIdx.x * 64;
  const int t = threadIdx.x;
#pragma unroll
  for (int i = 0; i < 16; ++i) {
    int idx = i * 256 + t;
    int r = idx >> 6, c = idx & 63;
    int l = l0 + r;
    size_t base = (size_t)l * 3072 + h * 64 + c;
    float q = qkv[base] + bqkv[h * 64 + c];
    Qs[((size_t)h * L + l) * 64 + c] = f2b(q * 0.125f);
    float k = qkv[base + 1024] + bqkv[1024 + h * 64 + c];
    if (l > 0) k += rel[(size_t)(l - 1) * 64 + c];
    Kp[((size_t)h * L + l) * 64 + c] = f2b(k);
    float v = qkv[base + 2048] + bqkv[2048 + h * 64 + c];
    vt[r][c] = f2b(v);
  }
  __syncthreads();
#pragma unroll
  for (int i = 0; i < 16; ++i) {
    int idx = i * 256 + t;
    int r = idx >> 6, c = idx & 63;  // r = d index, c = l index
    Vt[((size_t)h * 64 + r) * L + l0 + c] = vt[c][r];
  }
}

// ---------------- flash attention ----------------
// Qs: [H][L][64] bf16 (pre-scaled), Kp: [H][L][64] bf16, Vt: [H][64][L] bf16
// O: [L][1024] bf16. 4 waves/block, 16 q-rows/wave, 64-key tiles.
__global__ __launch_bounds__(256) void attn(const ushort* __restrict__ Qs,
                                            const ushort* __restrict__ Kp,
                                            const ushort* __restrict__ Vt,
                                            ushort* __restrict__ O, int L) {
  __shared__ ushort plds[4][16 * 64];
  const int h = blockIdx.y;
  const int q0 = blockIdx.x * 64;
  const int t = threadIdx.x, lane = t & 63, w = t >> 6;
  const int qbase = q0 + w * 16;
  const ushort* qh = Qs + ((size_t)h * L + qbase) * 64;
  const ushort* kh = Kp + (size_t)h * L * 64;
  const ushort* vh = Vt + (size_t)h * 64 * L;

  bf16x8 qf[2];
  {
    int row = lane & 15, d0 = (lane >> 4) * 8;
    qf[0] = *(const bf16x8*)(qh + (size_t)row * 64 + d0);
    qf[1] = *(const bf16x8*)(qh + (size_t)row * 64 + 32 + d0);
  }
  float mrun[4], lrun[4];
  f32x4 oacc[4] = {};
#pragma unroll
  for (int r = 0; r < 4; ++r) { mrun[r] = -1e30f; lrun[r] = 0.f; }

  char* myp = (char*)&plds[w][0];
  const int prow = lane & 15;
  const int myxor = (prow & 7) << 4;

  for (int kt = 0; kt < L; kt += 64) {
    // S = Q K'^T for 4 16-key subtiles
    f32x4 s[4];
#pragma unroll
    for (int j = 0; j < 4; ++j) {
      const ushort* kp = kh + (size_t)(kt + j * 16 + (lane & 15)) * 64 + (lane >> 4) * 8;
      bf16x8 k0 = *(const bf16x8*)kp;
      bf16x8 k1 = *(const bf16x8*)(kp + 32);
      f32x4 z = {};
      z = MFMA16(qf[0], k0, z);
      z = MFMA16(qf[1], k1, z);
      s[j] = z;
    }
    // online softmax per q-row (rows (lane>>4)*4+r; 16 lanes of a group hold 16 cols)
#pragma unroll
    for (int r = 0; r < 4; ++r) {
      float v = fmaxf(fmaxf(s[0][r], s[1][r]), fmaxf(s[2][r], s[3][r]));
      v = fmaxf(v, __shfl_xor(v, 1, 64));
      v = fmaxf(v, __shfl_xor(v, 2, 64));
      v = fmaxf(v, __shfl_xor(v, 4, 64));
      v = fmaxf(v, __shfl_xor(v, 8, 64));
      float mn = fmaxf(mrun[r], v);
      float sc = __expf(mrun[r] - mn);
      mrun[r] = mn;
      lrun[r] *= sc;
#pragma unroll
      for (int j = 0; j < 4; ++j) oacc[j][r] *= sc;
      float rs = 0.f;
      int rg = ((lane >> 4) << 2) + r;
      int rx = (rg & 7) << 4;
#pragma unroll
      for (int j = 0; j < 4; ++j) {
        float p = __expf(s[j][r] - mn);
        rs += p;
        int cb = (j * 16 + (lane & 15)) * 2;
        *(ushort*)(myp + rg * 128 + (cb ^ rx)) = f2b(p);
      }
      rs += __shfl_xor(rs, 1, 64);
      rs += __shfl_xor(rs, 2, 64);
      rs += __shfl_xor(rs, 4, 64);
      rs += __shfl_xor(rs, 8, 64);
      lrun[r] += rs;
    }
    // PV: read P back in A-fragment layout (same-wave LDS round trip)
    bf16x8 pa[2];
#pragma unroll
    for (int c = 0; c < 2; ++c) {
      int cb = c * 64 + ((lane >> 4) << 4);
      pa[c] = *(const bf16x8*)(myp + prow * 128 + (cb ^ myxor));
    }
#pragma unroll
    for (int j = 0; j < 4; ++j) {
      const ushort* vp = vh + (size_t)(j * 16 + (lane & 15)) * L + kt + (lane >> 4) * 8;
      bf16x8 v0 = *(const bf16x8*)vp;
      bf16x8 v1 = *(const bf16x8*)(vp + 32);
      oacc[j] = MFMA16(pa[0], v0, oacc[j]);
      oacc[j] = MFMA16(pa[1], v1, oacc[j]);
    }
  }
#pragma unroll
  for (int j = 0; j < 4; ++j) {
#pragma unroll
    for (int r = 0; r < 4; ++r) {
      int row = qbase + ((lane >> 4) << 2) + r;
      int col = h * 64 + j * 16 + (lane & 15);
      O[(size_t)row * 1024 + col] = f2b(oacc[j][r] / lrun[r]);
    }
  }
}

extern "C" void kernel_launch(void* const* d_in, const int* in_sizes, int n_in,
                              void* d_out, int out_size, void* d_ws, size_t ws_size,
                              hipStream_t stream) {
  (void)n_in; (void)out_size; (void)ws_size;
  const float* x    = (const float*)d_in[0];
  const float* Wqkv = (const float*)d_in[1];
  const float* bqkv = (const float*)d_in[2];
  const float* Wout = (const float*)d_in[3];
  const float* bout = (const float*)d_in[4];
  const float* rel  = (const float*)d_in[5];
  float* out = (float*)d_out;
  const int L = in_sizes[0] / 1024;  // 2048

  char* ws = (char*)d_ws;
  const size_t MB = 1024 * 1024;
  ushort* xb  = (ushort*)(ws);             // L*1024 bf16      (4 MB)
  ushort* w1t = (ushort*)(ws + 4 * MB);    // [3072][1024] bf16 (6 MB)
  ushort* w2t = (ushort*)(ws + 10 * MB);   // [1024][1024] bf16 (2 MB)
  float*  qkv = (float*)(ws + 12 * MB);    // [L][3072] fp32   (24 MB)
  ushort* Qsb = (ushort*)(ws + 36 * MB);   // [16][L][64] bf16  (4 MB)
  ushort* Kpb = (ushort*)(ws + 40 * MB);   // [16][L][64] bf16  (4 MB)
  ushort* Vtb = (ushort*)(ws + 44 * MB);   // [16][64][L] bf16  (4 MB)
  ushort* Ob  = (ushort*)(ws + 48 * MB);   // [L][1024] bf16    (4 MB)

  cvt_x<<<dim3((L * 1024) / (256 * 4)), 256, 0, stream>>>(x, xb, L * 1024);
  transpose_w<<<dim3(3072 / 64, 1024 / 64), 256, 0, stream>>>(Wqkv, w1t, 1024, 3072);
  transpose_w<<<dim3(1024 / 64, 1024 / 64), 256, 0, stream>>>(Wout, w2t, 1024, 1024);
  gemm_bt<false><<<dim3(3072 / 128, L / 128), 256, 0, stream>>>(xb, w1t, qkv, nullptr, L, 3072, 1024);
  pack_qkv<<<dim3(L / 64, 16), 256, 0, stream>>>(qkv, bqkv, rel, Qsb, Kpb, Vtb, L);
  attn<<<dim3(L / 64, 16), 256, 0, stream>>>(Qsb, Kpb, Vtb, Ob, L);
  gemm_bt<true><<<dim3(1024 / 128, L / 128), 256, 0, stream>>>(Ob, w2t, out, bout, L, 1024, 1024);
}

// Round 2
// 136.145 us; speedup vs baseline: 1.5247x; 1.5247x over previous
//
#include <hip/hip_runtime.h>
#include <hip/hip_bf16.h>
#include <stdint.h>

typedef __attribute__((ext_vector_type(8))) __bf16 bf16x8;
typedef __attribute__((ext_vector_type(4))) float f32x4;
typedef __attribute__((ext_vector_type(16))) float f32x16;

#define MFMA16(a, b, c) __builtin_amdgcn_mfma_f32_16x16x32_bf16(a, b, c, 0, 0, 0)
#define MFMA32(a, b, c) __builtin_amdgcn_mfma_f32_32x32x16_bf16(a, b, c, 0, 0, 0)

typedef const __attribute__((address_space(1))) uint32_t* gas_ptr;
typedef __attribute__((address_space(3))) uint32_t* lds_ptr;

static __device__ __forceinline__ ushort f2b(float f) {
  union { float f; uint32_t u; } x; x.f = f;
  uint32_t u = x.u + 0x7fffu + ((x.u >> 16) & 1u);
  return (ushort)(u >> 16);
}

static __device__ __forceinline__ void g2lds16(const void* g, void* l) {
  __builtin_amdgcn_global_load_lds((gas_ptr)(uintptr_t)g, (lds_ptr)(uintptr_t)l, 16, 0, 0);
}

// ---------------- x fp32 -> bf16 ----------------
__global__ void cvt_x(const float* __restrict__ in, ushort* __restrict__ out, int n) {
  int i = (blockIdx.x * blockDim.x + threadIdx.x) * 4;
  if (i < n) {
    float4 v = *(const float4*)(in + i);
    ushort4 o;
    o.x = f2b(v.x); o.y = f2b(v.y); o.z = f2b(v.z); o.w = f2b(v.w);
    *(ushort4*)(out + i) = o;
  }
}

// ---------------- W fp32 [K][N] -> bf16 [N][K] (B^T layout) ----------------
__global__ __launch_bounds__(256) void transpose_w(const float* __restrict__ in,
                                                   ushort* __restrict__ out, int K, int N) {
  __shared__ ushort tile[64][65];
  int n0 = blockIdx.x * 64, k0 = blockIdx.y * 64;
  int t = threadIdx.x;
#pragma unroll
  for (int i = 0; i < 16; ++i) {
    int idx = i * 256 + t;
    int r = idx >> 6, c = idx & 63;
    tile[r][c] = f2b(in[(size_t)(k0 + r) * N + n0 + c]);
  }
  __syncthreads();
#pragma unroll
  for (int i = 0; i < 16; ++i) {
    int idx = i * 256 + t;
    int r = idx >> 6, c = idx & 63;  // r = n index, c = k index
    out[(size_t)(n0 + r) * K + k0 + c] = tile[c][r];
  }
}

// ---------------- bf16 GEMM: C[M][N] = A[M][K] * Bt[N][K]^T (+bias) ----------------
template <bool BIAS>
__global__ __launch_bounds__(256) void gemm_bt(const ushort* __restrict__ A,
                                               const ushort* __restrict__ Bt,
                                               float* __restrict__ C,
                                               const float* __restrict__ bias,
                                               int M, int N, int K) {
  __shared__ ushort lA[128 * 64];
  __shared__ ushort lB[128 * 64];
  const int t = threadIdx.x;
  const int lane = t & 63;
  const int bm = blockIdx.y * 128, bn = blockIdx.x * 128;
  const int wid = t >> 6, wr = wid >> 1, wc = wid & 1;

  f32x4 acc[4][4] = {};

  for (int k0 = 0; k0 < K; k0 += 64) {
#pragma unroll
    for (int i = 0; i < 4; ++i) {
      int ci = i * 256 + t;
      int r = ci >> 3, cs = ci & 7;
      int cg = (cs ^ (r & 7)) * 8;
      g2lds16(A + (size_t)(bm + r) * K + k0 + cg, (ushort*)lA + ci * 8);
      g2lds16(Bt + (size_t)(bn + r) * K + k0 + cg, (ushort*)lB + ci * 8);
    }
    __syncthreads();
#pragma unroll
    for (int kk = 0; kk < 2; ++kk) {
      bf16x8 af[4], bfr[4];
#pragma unroll
      for (int m = 0; m < 4; ++m) {
        int row = wr * 64 + m * 16 + (lane & 15);
        int cb = kk * 64 + ((lane >> 4) << 4);
        int sw = cb ^ ((row & 7) << 4);
        af[m] = *(const bf16x8*)((const char*)lA + row * 128 + sw);
      }
#pragma unroll
      for (int n = 0; n < 4; ++n) {
        int row = wc * 64 + n * 16 + (lane & 15);
        int cb = kk * 64 + ((lane >> 4) << 4);
        int sw = cb ^ ((row & 7) << 4);
        bfr[n] = *(const bf16x8*)((const char*)lB + row * 128 + sw);
      }
#pragma unroll
      for (int m = 0; m < 4; ++m)
#pragma unroll
        for (int n = 0; n < 4; ++n) acc[m][n] = MFMA16(af[m], bfr[n], acc[m][n]);
    }
    __syncthreads();
  }
#pragma unroll
  for (int m = 0; m < 4; ++m) {
#pragma unroll
    for (int n = 0; n < 4; ++n) {
      int col = bn + wc * 64 + n * 16 + (lane & 15);
      float b = BIAS ? bias[col] : 0.f;
#pragma unroll
      for (int r = 0; r < 4; ++r) {
        int row = bm + wr * 64 + m * 16 + ((lane >> 4) << 2) + r;
        C[(size_t)row * N + col] = acc[m][n][r] + b;
      }
    }
  }
}

// ---------------- split qkv fp32 -> Qs (x 0.125*log2e), K' (+rel), V^T, all bf16 ----------------
__global__ __launch_bounds__(256) void pack_qkv(const float* __restrict__ qkv,
                                                const float* __restrict__ bqkv,
                                                const float* __restrict__ rel,
                                                ushort* __restrict__ Qs,
                                                ushort* __restrict__ Kp,
                                                ushort* __restrict__ Vt, int L) {
  __shared__ ushort vt[64][65];
  const int h = blockIdx.y;
  const int l0 = blockIdx.x * 64;
  const int t = threadIdx.x;
#pragma unroll
  for (int i = 0; i < 16; ++i) {
    int idx = i * 256 + t;
    int r = idx >> 6, c = idx & 63;
    int l = l0 + r;
    size_t base = (size_t)l * 3072 + h * 64 + c;
    float q = qkv[base] + bqkv[h * 64 + c];
    Qs[((size_t)h * L + l) * 64 + c] = f2b(q * 0.18033688f);  // 0.125 * log2(e)
    float k = qkv[base + 1024] + bqkv[1024 + h * 64 + c];
    if (l > 0) k += rel[(size_t)(l - 1) * 64 + c];
    Kp[((size_t)h * L + l) * 64 + c] = f2b(k);
    float v = qkv[base + 2048] + bqkv[2048 + h * 64 + c];
    vt[r][c] = f2b(v);
  }
  __syncthreads();
#pragma unroll
  for (int i = 0; i < 16; ++i) {
    int idx = i * 256 + t;
    int r = idx >> 6, c = idx & 63;  // r = d index, c = l index
    Vt[((size_t)h * 64 + r) * L + l0 + c] = vt[c][r];
  }
}

// ---------------- flash attention, swapped-operand 32x32 ----------------
// Qs: [H][L][64] bf16 (pre-scaled by 0.125*log2e), Kp: [H][L][64] bf16, Vt: [H][64][L] bf16
// O: [L][1024] bf16.
// Block: 256 thr = 4 waves. wave w: q-tile (w&1) of 32 rows, key-half (w>>1).
// Per wave: S^T = K*Q^T (32x32x16 mfma, swapped) -> lane-local softmax over 32 k
// (one shfl_xor(32) completes the 64-wide row) -> cvt_pk+half-swap -> O^T += V^T*P^T.
// exp2 domain; defer-max THR=8; LDS flash-merge of the two key-halves.
__global__ __launch_bounds__(256) void attn2(const ushort* __restrict__ Qs,
                                             const ushort* __restrict__ Kp,
                                             const ushort* __restrict__ Vt,
                                             ushort* __restrict__ O, int L) {
  __shared__ float OTb[2][2][32][68];  // [qtile][ksplit][q][d] (pad 68)
  __shared__ float mb[2][2][32];
  __shared__ float lb[2][2][32];
  const int h = blockIdx.y;
  const int q064 = blockIdx.x * 64;
  const int t = threadIdx.x, lane = t & 63, w = t >> 6;
  const int qt = w & 1, ks = w >> 1;
  const int ql = lane & 31, hi = lane >> 5;
  const bool lo = (hi == 0);
  const ushort* qrow = Qs + ((size_t)h * L + q064 + qt * 32 + ql) * 64 + hi * 8;
  const ushort* kh = Kp + (size_t)h * L * 64;
  const ushort* vh = Vt + (size_t)h * 64 * L;
  const int kbeg = ks * (L >> 1), kend = kbeg + (L >> 1);

  bf16x8 qf[4];
#pragma unroll
  for (int c = 0; c < 4; ++c) qf[c] = *(const bf16x8*)(qrow + c * 16);

  f32x16 ot0 = {}, ot1 = {};
  float m = -1e30f, l = 0.f;

  for (int kt = kbeg; kt < kend; kt += 64) {
    // S^T: two 32x32 tiles (keys kt..kt+31, kt+32..kt+63). A = K rows, B = Q row frags.
    const ushort* kp0 = kh + (size_t)(kt + ql) * 64 + hi * 8;
    f32x16 s0 = {}, s1 = {};
#pragma unroll
    for (int c = 0; c < 4; ++c) {
      bf16x8 kf = *(const bf16x8*)(kp0 + c * 16);
      s0 = MFMA32(kf, qf[c], s0);
    }
#pragma unroll
    for (int c = 0; c < 4; ++c) {
      bf16x8 kf = *(const bf16x8*)(kp0 + 32 * 64 + c * 16);
      s1 = MFMA32(kf, qf[c], s1);
    }
    // row max: 31 in-register + 1 cross-half
    float mx = fmaxf(s0[0], s1[0]);
#pragma unroll
    for (int i = 1; i < 16; ++i) mx = fmaxf(mx, fmaxf(s0[i], s1[i]));
    mx = fmaxf(mx, __shfl_xor(mx, 32, 64));
    if (!__all(mx - m <= 8.0f)) {   // defer-max (T13)
      float mn = fmaxf(m, mx);
      float sc = __builtin_amdgcn_exp2f(m - mn);
      m = mn;
      l *= sc;
      ot0 = ot0 * sc;
      ot1 = ot1 * sc;
    }
    float rs = 0.f;
#pragma unroll
    for (int tl = 0; tl < 2; ++tl) {
      f32x16 s = tl ? s1 : s0;
      float p[16];
#pragma unroll
      for (int i = 0; i < 16; ++i) {
        p[i] = __builtin_amdgcn_exp2f(s[i] - m);
        rs += p[i];
      }
      // pack to bf16 pairs; exchange halves so each lane holds contiguous-k B-frag words
      uint32_t a[8], x[8];
#pragma unroll
      for (int i = 0; i < 8; ++i) {
        uint32_t r;
        asm("v_cvt_pk_bf16_f32 %0, %1, %2" : "=v"(r) : "v"(p[2 * i]), "v"(p[2 * i + 1]));
        a[i] = r;
      }
#pragma unroll
      for (int i = 0; i < 8; ++i) x[i] = __shfl_xor(a[i], 32, 64);
      union { uint32_t u[4]; bf16x8 v; } b0, b1;
      b0.u[0] = lo ? a[0] : x[2];
      b0.u[1] = lo ? a[1] : x[3];
      b0.u[2] = lo ? x[0] : a[2];
      b0.u[3] = lo ? x[1] : a[3];
      b1.u[0] = lo ? a[4] : x[6];
      b1.u[1] = lo ? a[5] : x[7];
      b1.u[2] = lo ? x[4] : a[6];
      b1.u[3] = lo ? x[5] : a[7];
      // PV: O^T += V^T * P^T  (A = V^T rows, natural loads from Vt)
      const ushort* vb = vh + (size_t)ql * L + kt + tl * 32 + hi * 8;
      bf16x8 v00 = *(const bf16x8*)vb;
      bf16x8 v01 = *(const bf16x8*)(vb + 16);
      bf16x8 v10 = *(const bf16x8*)(vb + (size_t)32 * L);
      bf16x8 v11 = *(const bf16x8*)(vb + (size_t)32 * L + 16);
      ot0 = MFMA32(v00, b0.v, ot0);
      ot0 = MFMA32(v01, b1.v, ot0);
      ot1 = MFMA32(v10, b0.v, ot1);
      ot1 = MFMA32(v11, b1.v, ot1);
    }
    rs += __shfl_xor(rs, 32, 64);
    l += rs;
  }

  // ---- flash-merge the two key-halves via LDS ----
  if (lo) mb[qt][ks][ql] = m;
  __syncthreads();
  {
    float mo = mb[qt][ks ^ 1][ql];
    float mn = fmaxf(m, mo);
    float f = __builtin_amdgcn_exp2f(m - mn);
    l *= f;
    ot0 = ot0 * f;
    ot1 = ot1 * f;
  }
  if (lo) lb[qt][ks][ql] = l;
#pragma unroll
  for (int r = 0; r < 16; ++r) {
    int d = (r & 3) + 8 * (r >> 2) + 4 * hi;
    OTb[qt][ks][ql][d] = ot0[r];
    OTb[qt][ks][ql][32 + d] = ot1[r];
  }
  __syncthreads();
  // final combine + transpose + coalesced store; wave (qt,ks) takes rows ks*16..+15
#pragma unroll
  for (int i = 0; i < 2; ++i) {
    int row = ks * 16 + i * 8 + (lane >> 3);
    int d0 = (lane & 7) * 8;
    float4 a0 = *(const float4*)&OTb[qt][0][row][d0];
    float4 a1 = *(const float4*)&OTb[qt][0][row][d0 + 4];
    float4 c0 = *(const float4*)&OTb[qt][1][row][d0];
    float4 c1 = *(const float4*)&OTb[qt][1][row][d0 + 4];
    float inv = 1.0f / (lb[qt][0][row] + lb[qt][1][row]);
    union { ushort us[8]; uint4 u4; } o;
    o.us[0] = f2b((a0.x + c0.x) * inv);
    o.us[1] = f2b((a0.y + c0.y) * inv);
    o.us[2] = f2b((a0.z + c0.z) * inv);
    o.us[3] = f2b((a0.w + c0.w) * inv);
    o.us[4] = f2b((a1.x + c1.x) * inv);
    o.us[5] = f2b((a1.y + c1.y) * inv);
    o.us[6] = f2b((a1.z + c1.z) * inv);
    o.us[7] = f2b((a1.w + c1.w) * inv);
    *(uint4*)(O + (size_t)(q064 + qt * 32 + row) * 1024 + h * 64 + d0) = o.u4;
  }
}

extern "C" void kernel_launch(void* const* d_in, const int* in_sizes, int n_in,
                              void* d_out, int out_size, void* d_ws, size_t ws_size,
                              hipStream_t stream) {
  (void)n_in; (void)out_size; (void)ws_size;
  const float* x    = (const float*)d_in[0];
  const float* Wqkv = (const float*)d_in[1];
  const float* bqkv = (const float*)d_in[2];
  const float* Wout = (const float*)d_in[3];
  const float* bout = (const float*)d_in[4];
  const float* rel  = (const float*)d_in[5];
  float* out = (float*)d_out;
  const int L = in_sizes[0] / 1024;  // 2048

  char* ws = (char*)d_ws;
  const size_t MB = 1024 * 1024;
  ushort* xb  = (ushort*)(ws);             // L*1024 bf16       (4 MB)
  ushort* w1t = (ushort*)(ws + 4 * MB);    // [3072][1024] bf16 (6 MB)
  ushort* w2t = (ushort*)(ws + 10 * MB);   // [1024][1024] bf16 (2 MB)
  float*  qkv = (float*)(ws + 12 * MB);    // [L][3072] fp32    (24 MB)
  ushort* Qsb = (ushort*)(ws + 36 * MB);   // [16][L][64] bf16  (4 MB)
  ushort* Kpb = (ushort*)(ws + 40 * MB);   // [16][L][64] bf16  (4 MB)
  ushort* Vtb = (ushort*)(ws + 44 * MB);   // [16][64][L] bf16  (4 MB)
  ushort* Ob  = (ushort*)(ws + 48 * MB);   // [L][1024] bf16    (4 MB)

  cvt_x<<<dim3((L * 1024) / (256 * 4)), 256, 0, stream>>>(x, xb, L * 1024);
  transpose_w<<<dim3(3072 / 64, 1024 / 64), 256, 0, stream>>>(Wqkv, w1t, 1024, 3072);
  transpose_w<<<dim3(1024 / 64, 1024 / 64), 256, 0, stream>>>(Wout, w2t, 1024, 1024);
  gemm_bt<false><<<dim3(3072 / 128, L / 128), 256, 0, stream>>>(xb, w1t, qkv, nullptr, L, 3072, 1024);
  pack_qkv<<<dim3(L / 64, 16), 256, 0, stream>>>(qkv, bqkv, rel, Qsb, Kpb, Vtb, L);
  attn2<<<dim3(L / 64, 16), 256, 0, stream>>>(Qsb, Kpb, Vtb, Ob, L);
  gemm_bt<true><<<dim3(1024 / 128, L / 128), 256, 0, stream>>>(Ob, w2t, out, bout, L, 1024, 1024);
}